// Round 1
// baseline (525.845 us; speedup 1.0000x reference)
//
#include <hip/hip_runtime.h>
#include <cstdint>
#include <cstddef>

#define C_DIM 256
#define N_PIX 4096
#define NHEAD 4
#define HD    16
#define RED   64
#define LOG2E 1.44269504088896340736f
// SCALE = HD^-0.5 = 0.25

// ---------------------------------------------------------------------------
// Kernel 1: LayerNorm + QKV projection + dynamic-weight branch (conv1/relu/conv2)
// One block = 32 pixels of one batch. x is [B][C][N] (N contiguous).
// Q/K/V stored as [B*NH][HD][N] (n contiguous -> coalesced for attention).
// ---------------------------------------------------------------------------
__global__ __launch_bounds__(256) void prep_kernel(
    const float* __restrict__ x, const float* __restrict__ nw, const float* __restrict__ nb,
    const float* __restrict__ qkv_w, const float* __restrict__ c1w, const float* __restrict__ c1b,
    const float* __restrict__ c2w, const float* __restrict__ c2b,
    float* __restrict__ Q, float* __restrict__ K, float* __restrict__ V,
    float* __restrict__ dynb)
{
    __shared__ float xs[C_DIM * 32];   // raw x tile  [c][j]
    __shared__ float xn[C_DIM * 32];   // normalized  [c][j]
    __shared__ float red[2 * 256];     // LN partials: 8 groups x 32 px (sum, sumsq)
    __shared__ float muS[32], rsS[32];
    __shared__ float dpart[8 * 32];

    const int t  = threadIdx.x;
    const int b  = blockIdx.x >> 7;          // 0..1
    const int n0 = (blockIdx.x & 127) * 32;  // pixel tile base
    const size_t xb = (size_t)b * C_DIM * N_PIX;

    // load x tile: f = c*32 + j, coalesced 32-float row segments
    for (int i = 0; i < 32; ++i) {
        int f = i * 256 + t;
        xs[f] = x[xb + (size_t)(f >> 5) * N_PIX + n0 + (f & 31)];
    }
    __syncthreads();

    const int j  = t & 31;
    const int cg = t >> 5;   // 0..7

    // LayerNorm partial sums over this thread's 32 channels
    {
        float s1 = 0.f, s2 = 0.f;
        for (int cc = 0; cc < 32; ++cc) {
            float v = xs[(cg * 32 + cc) * 32 + j];
            s1 += v; s2 += v * v;
        }
        red[cg * 32 + j] = s1;
        red[256 + cg * 32 + j] = s2;
    }
    __syncthreads();
    if (t < 32) {
        float su = 0.f, sq = 0.f;
        for (int g = 0; g < 8; ++g) { su += red[g * 32 + t]; sq += red[256 + g * 32 + t]; }
        float mu  = su * (1.f / C_DIM);
        float var = sq * (1.f / C_DIM) - mu * mu;
        muS[t] = mu;
        rsS[t] = rsqrtf(var + 1e-5f);
    }
    __syncthreads();
    {
        float mu = muS[j], rs = rsS[j];
        for (int cc = 0; cc < 32; ++cc) {
            int c = cg * 32 + cc;
            xn[c * 32 + j] = (xs[c * 32 + j] - mu) * rs * nw[c] + nb[c];
        }
    }
    __syncthreads();

    // fused GEMM: outputs 0..191 = qkv (reads xn), 192..319 = conv1 (reads xs)
    float dsum = 0.f;
    for (int o = cg * 40; o < cg * 40 + 40; ++o) {
        const float* wrow = (o < 192) ? (qkv_w + o * C_DIM) : (c1w + (o - 192) * C_DIM);
        const float* src  = (o < 192) ? xn : xs;
        const float4* w4  = (const float4*)wrow;
        float acc = 0.f;
        #pragma unroll 8
        for (int c4 = 0; c4 < 64; ++c4) {
            float4 wv = w4[c4];
            int cb = c4 * 4;
            acc += wv.x * src[cb * 32 + j];
            acc += wv.y * src[(cb + 1) * 32 + j];
            acc += wv.z * src[(cb + 2) * 32 + j];
            acc += wv.w * src[(cb + 3) * 32 + j];
        }
        if (o < 192) {
            int part = o >> 6;       // 0=q 1=k 2=v
            int rr   = o & 63;       // r within [0,64): h = rr>>4, d = rr&15
            float* dst = (part == 0) ? Q : (part == 1) ? K : V;
            dst[((size_t)(b * NHEAD + (rr >> 4)) * HD + (rr & 15)) * N_PIX + n0 + j] = acc;
        } else {
            int oc = o - 192;
            float r = fmaxf(acc + c1b[oc], 0.f);
            dsum += r * c2w[oc];
        }
    }
    dpart[cg * 32 + j] = dsum;
    __syncthreads();
    if (t < 32) {
        float dy = c2b[0];
        for (int g = 0; g < 8; ++g) dy += dpart[g * 32 + t];
        dynb[(size_t)b * N_PIX + n0 + t] = dy;
    }
}

// ---------------------------------------------------------------------------
// Kernel 2: flash attention. One block = (b,h) x 64 queries; 4-way key split.
// Thread t: query lane j = t&63, key-split s = t>>6.
// K/V staged 256 keys at a time in LDS as [d][m]; all lanes iterate the same
// key m -> same-address LDS broadcast (conflict-free).
// Epilogue merges the 4 splits and applies dyn[b,n]/l.
// ---------------------------------------------------------------------------
__global__ __launch_bounds__(256) void attn_kernel(
    const float* __restrict__ Q, const float* __restrict__ K, const float* __restrict__ V,
    const float* __restrict__ dynb, float* __restrict__ AO)
{
    __shared__ float smem[8192];     // kd[16*256] | vd[16*256]; reused for merge
    float* kd = smem;
    float* vd = smem + 4096;

    const int t  = threadIdx.x;
    const int bh = blockIdx.x >> 6;          // 0..7 = b*4+h
    const int n0 = (blockIdx.x & 63) * 64;
    const int j  = t & 63;
    const int s  = t >> 6;
    const int n  = n0 + j;
    const size_t base = (size_t)bh * HD * N_PIX;

    float q[HD];
    #pragma unroll
    for (int d = 0; d < HD; ++d)
        q[d] = Q[base + (size_t)d * N_PIX + n] * (0.25f * LOG2E);  // fold scale + log2(e)

    float m2 = -INFINITY, l = 0.f, o[HD];
    #pragma unroll
    for (int d = 0; d < HD; ++d) o[d] = 0.f;

    for (int tile = 0; tile < N_PIX / 256; ++tile) {
        __syncthreads();
        const int k0 = tile * 256;
        for (int i = 0; i < 16; ++i) {
            int f = i * 256 + t;
            int d = f >> 8, m = f & 255;
            kd[f] = K[base + (size_t)d * N_PIX + k0 + m];
            vd[f] = V[base + (size_t)d * N_PIX + k0 + m];
        }
        __syncthreads();

        const int mb = s * 64;
        for (int chunk = 0; chunk < 4; ++chunk) {
            float sc[16];
            #pragma unroll
            for (int mm = 0; mm < 16; ++mm) {
                int m = mb + chunk * 16 + mm;
                float acc = 0.f;
                #pragma unroll
                for (int d = 0; d < HD; ++d) acc += q[d] * kd[d * 256 + m];
                sc[mm] = acc;
            }
            float mx = sc[0];
            #pragma unroll
            for (int mm = 1; mm < 16; ++mm) mx = fmaxf(mx, sc[mm]);
            float mnew = fmaxf(m2, mx);
            float corr = exp2f(m2 - mnew);
            l *= corr;
            #pragma unroll
            for (int d = 0; d < HD; ++d) o[d] *= corr;
            m2 = mnew;
            #pragma unroll
            for (int mm = 0; mm < 16; ++mm) {
                int m = mb + chunk * 16 + mm;
                float p = exp2f(sc[mm] - m2);
                l += p;
                #pragma unroll
                for (int d = 0; d < HD; ++d) o[d] += p * vd[d * 256 + m];
            }
        }
    }
    __syncthreads();

    // merge the 4 key-splits: per (s,j) slot of 18 floats (o[16], m, l); stride 18
    // gives 2-way bank aliasing (free on CDNA4).
    float* mg = smem;
    {
        float* myb = mg + (s * 64 + j) * 18;
        #pragma unroll
        for (int d = 0; d < HD; ++d) myb[d] = o[d];
        myb[16] = m2;
        myb[17] = l;
    }
    __syncthreads();
    if (t < 64) {
        float M = -INFINITY;
        for (int s2 = 0; s2 < 4; ++s2) M = fmaxf(M, mg[(s2 * 64 + j) * 18 + 16]);
        float L = 0.f, O[HD];
        #pragma unroll
        for (int d = 0; d < HD; ++d) O[d] = 0.f;
        for (int s2 = 0; s2 < 4; ++s2) {
            const float* ob = mg + (s2 * 64 + j) * 18;
            float cc = exp2f(ob[16] - M);
            L += cc * ob[17];
            #pragma unroll
            for (int d = 0; d < HD; ++d) O[d] += cc * ob[d];
        }
        int b = bh >> 2;
        float scale = dynb[(size_t)b * N_PIX + n] / L;   // row-scale by dyn, /softmax denom
        #pragma unroll
        for (int d = 0; d < HD; ++d)
            AO[((size_t)bh * HD + d) * N_PIX + n] = O[d] * scale;
    }
}

// ---------------------------------------------------------------------------
// Kernel 3: out-projection [C=256 x RED=64] + sigmoid(gamma*y + x) epilogue.
// One block = 32 pixels of one batch; attn_out tile staged in LDS.
// ---------------------------------------------------------------------------
__global__ __launch_bounds__(256) void final_kernel(
    const float* __restrict__ AO, const float* __restrict__ out_w,
    const float* __restrict__ x, const float* __restrict__ gamma,
    float* __restrict__ out)
{
    __shared__ float a[RED * 32];   // [r][j]
    const int t  = threadIdx.x;
    const int b  = blockIdx.x >> 7;
    const int n0 = (blockIdx.x & 127) * 32;

    for (int i = 0; i < 8; ++i) {
        int f = i * 256 + t;
        a[f] = AO[((size_t)b * RED + (f >> 5)) * N_PIX + n0 + (f & 31)];
    }
    __syncthreads();

    const int j  = t & 31;
    const int cg = t >> 5;
    const float g = gamma[0];

    for (int k = 0; k < 32; ++k) {
        int c = cg * 32 + k;
        const float4* w4 = (const float4*)(out_w + c * RED);
        float acc = 0.f;
        #pragma unroll
        for (int r4 = 0; r4 < 16; ++r4) {
            float4 wv = w4[r4];
            int rb = r4 * 4;
            acc += wv.x * a[rb * 32 + j];
            acc += wv.y * a[(rb + 1) * 32 + j];
            acc += wv.z * a[(rb + 2) * 32 + j];
            acc += wv.w * a[(rb + 3) * 32 + j];
        }
        size_t idx = ((size_t)b * C_DIM + c) * N_PIX + n0 + j;
        float z = g * acc + x[idx];
        out[idx] = 1.f / (1.f + exp2f(-z * LOG2E));
    }
}

// ---------------------------------------------------------------------------
extern "C" void kernel_launch(void* const* d_in, const int* in_sizes, int n_in,
                              void* d_out, int out_size, void* d_ws, size_t ws_size,
                              hipStream_t stream)
{
    const float* x      = (const float*)d_in[0];
    const float* norm_w = (const float*)d_in[1];
    const float* norm_b = (const float*)d_in[2];
    const float* qkv_w  = (const float*)d_in[3];
    const float* out_w  = (const float*)d_in[4];
    const float* c1w    = (const float*)d_in[5];
    const float* c1b    = (const float*)d_in[6];
    const float* c2w    = (const float*)d_in[7];
    const float* c2b    = (const float*)d_in[8];
    const float* gamma  = (const float*)d_in[9];

    float* ws   = (float*)d_ws;
    float* Q    = ws;                 // [8][16][4096]
    float* K    = Q + 524288;
    float* V    = K + 524288;
    float* dynb = V + 524288;         // [2][4096]
    float* AO   = dynb + 8192;        // [2][64][4096]

    hipLaunchKernelGGL(prep_kernel, dim3(2 * (N_PIX / 32)), dim3(256), 0, stream,
                       x, norm_w, norm_b, qkv_w, c1w, c1b, c2w, c2b, Q, K, V, dynb);
    hipLaunchKernelGGL(attn_kernel, dim3(2 * NHEAD * (N_PIX / 64)), dim3(256), 0, stream,
                       Q, K, V, dynb, AO);
    hipLaunchKernelGGL(final_kernel, dim3(2 * (N_PIX / 32)), dim3(256), 0, stream,
                       AO, out_w, x, gamma, (float*)d_out);
}

// Round 2
// 259.350 us; speedup vs baseline: 2.0275x; 2.0275x over previous
//
#include <hip/hip_runtime.h>
#include <cstdint>
#include <cstddef>

#define LOG2E 1.44269504088896340736f

typedef float  f32x16 __attribute__((ext_vector_type(16)));
typedef __bf16 bf16x8 __attribute__((ext_vector_type(8)));

union BF8 { bf16x8 v; uint u[4]; ushort us[8]; };

__device__ __forceinline__ ushort f2bf(float f) {           // RNE
    uint u = __float_as_uint(f);
    u += 0x7FFFu + ((u >> 16) & 1u);
    return (ushort)(u >> 16);
}
// pack two floats to bf16 pair (round-half-up), a -> lo16, b -> hi16
__device__ __forceinline__ uint pack_bf(float a, float b) {
    uint ua = __float_as_uint(a) + 0x8000u;
    uint ub = __float_as_uint(b) + 0x8000u;
    return __builtin_amdgcn_perm(ub, ua, 0x07060302u);
}

// ---------------------------------------------------------------------------
// prep: x-tile (64 px) -> LayerNorm (in-place, qkv blocks only) -> GEMM with
// s-reg weights -> Qb/Kb [bh][n][16] bf16 (Q pre-scaled 0.25*log2e),
// Vsw swizzled [bh][key>>2][d][key&3] bf16, dynb (conv blocks).
// grid 256 = 2 b * 64 tiles * 2 S(out-split). block 256.
// ---------------------------------------------------------------------------
__global__ __launch_bounds__(256) void prep_kernel(
    const float* __restrict__ x, const float* __restrict__ nw, const float* __restrict__ nb,
    const float* __restrict__ qkv_w, const float* __restrict__ c1w, const float* __restrict__ c1b,
    const float* __restrict__ c2w, const float* __restrict__ c2b,
    ushort* __restrict__ Qb, ushort* __restrict__ Kb, ushort* __restrict__ Vsw,
    float* __restrict__ dynb)
{
    __shared__ float xs[64 * 260];      // [px][c], stride 260 dwords (16B aligned rows)
    __shared__ float qt[192 * 64];      // [o][px] (qkv blocks)
    __shared__ float red1[256], red2[256];
    __shared__ float muS[64], rsS[64];
    __shared__ float dpart[4 * 64];

    const int t    = threadIdx.x;
    const int bi   = blockIdx.x;
    const int S    = bi & 1;                 // 0 = qkv (192 outs), 1 = conv (128 outs)
    const int tile = (bi >> 1) & 63;
    const int b    = bi >> 7;
    const int n0   = tile * 64;
    const size_t xb = (size_t)b * 256 * 4096;

    // load x tile (coalesced), transpose to [px][c]
    for (int i = 0; i < 64; ++i) {
        int f = i * 256 + t;                 // f = c*64 + px
        int cc = f >> 6, px = f & 63;
        xs[px * 260 + cc] = x[xb + (size_t)cc * 4096 + n0 + px];
    }
    __syncthreads();

    if (S == 0) {
        // LN stats: px = t>>2, seg = t&3 (16 float4 each)
        {
            int px = t >> 2, seg = t & 3;
            const float4* rp = (const float4*)(xs + px * 260);
            float s1 = 0.f, s2 = 0.f;
            for (int k = seg * 16; k < seg * 16 + 16; ++k) {
                float4 v = rp[k];
                s1 += (v.x + v.y) + (v.z + v.w);
                s2 += v.x * v.x + v.y * v.y + v.z * v.z + v.w * v.w;
            }
            red1[t] = s1; red2[t] = s2;
        }
        __syncthreads();
        if (t < 64) {
            float s1 = red1[t*4] + red1[t*4+1] + red1[t*4+2] + red1[t*4+3];
            float s2 = red2[t*4] + red2[t*4+1] + red2[t*4+2] + red2[t*4+3];
            float mu = s1 * (1.f / 256.f);
            float var = s2 * (1.f / 256.f) - mu * mu;
            muS[t] = mu; rsS[t] = rsqrtf(fmaxf(var, 0.f) + 1e-5f);
        }
        __syncthreads();
        // normalize in place
        {
            int px = t >> 2, seg = t & 3;
            float mu = muS[px], rs = rsS[px];
            float4* rp = (float4*)(xs + px * 260);
            for (int k = seg * 16; k < seg * 16 + 16; ++k) {
                float4 v = rp[k];
                int cc = k * 4;
                v.x = (v.x - mu) * rs * nw[cc]   + nb[cc];
                v.y = (v.y - mu) * rs * nw[cc+1] + nb[cc+1];
                v.z = (v.z - mu) * rs * nw[cc+2] + nb[cc+2];
                v.w = (v.w - mu) * rs * nw[cc+3] + nb[cc+3];
                rp[k] = v;
            }
        }
        __syncthreads();
    }

    // GEMM: wave-uniform out ranges, s-reg weights, lane = px
    const int w    = t >> 6;
    const int lane = t & 63;
    const int ob   = __builtin_amdgcn_readfirstlane(S ? (w * 32) : (w * 48));
    const float* Wb = S ? (c1w + (size_t)ob * 256) : (qkv_w + (size_t)ob * 256);
    const int NCH  = S ? 2 : 3;                // chunks of 16 outs

    float acc[48];
    #pragma unroll
    for (int i = 0; i < 48; ++i) acc[i] = 0.f;

    const float4* sv = (const float4*)(xs + lane * 260);
    for (int chk = 0; chk < NCH; ++chk) {
        const float* wc = Wb + (size_t)chk * 16 * 256;
        float* ac = acc + chk * 16;
        #pragma unroll 2
        for (int c4 = 0; c4 < 64; ++c4) {
            float4 xv = sv[c4];
            #pragma unroll
            for (int o = 0; o < 16; ++o) {
                const float4 wv = *(const float4*)(wc + o * 256 + c4 * 4);
                ac[o] += wv.x * xv.x + wv.y * xv.y + wv.z * xv.z + wv.w * xv.w;
            }
        }
    }

    if (S) {
        // conv epilogue: relu, *c2w, reduce over 128 channels -> dyn
        float ds = 0.f;
        #pragma unroll
        for (int i = 0; i < 32; ++i) {
            int oc = ob + i;
            float r = fmaxf(acc[i] + c1b[oc], 0.f);
            ds += r * c2w[oc];
        }
        dpart[w * 64 + lane] = ds;
        __syncthreads();
        if (t < 64) {
            float dy = c2b[0] + dpart[t] + dpart[64 + t] + dpart[128 + t] + dpart[192 + t];
            dynb[(size_t)b * 4096 + n0 + t] = dy;
        }
        return;
    }

    // qkv epilogue: stash then write bf16 layouts
    #pragma unroll
    for (int i = 0; i < 48; ++i) qt[(ob + i) * 64 + lane] = acc[i];
    __syncthreads();

    const float qscale = 0.25f * LOG2E;
    for (int i = 0; i < 16; ++i) {               // Qb / Kb rows
        int idx = i * 256 + t;                   // 0..4095
        int part = idx >> 11;
        int rem  = idx & 2047;
        int hh = rem >> 9;
        int px = (rem >> 3) & 63;
        int d2 = rem & 7;
        int o  = part * 64 + hh * 16 + d2 * 2;
        float v0 = qt[o * 64 + px], v1 = qt[(o + 1) * 64 + px];
        if (part == 0) { v0 *= qscale; v1 *= qscale; }
        uint pk = (uint)f2bf(v0) | ((uint)f2bf(v1) << 16);
        ushort* dst = part ? Kb : Qb;
        *(uint*)(dst + (((size_t)(b * 4 + hh) * 4096 + n0 + px) * 16 + d2 * 2)) = pk;
    }
    for (int i = 0; i < 4; ++i) {                // Vsw swizzled
        int idx = i * 256 + t;                   // 0..1023
        int hh = idx >> 8;
        int sg = (idx >> 4) & 15;
        int d  = idx & 15;
        const float* src = qt + (128 + hh * 16 + d) * 64 + sg * 4;
        uint lo = (uint)f2bf(src[0]) | ((uint)f2bf(src[1]) << 16);
        uint hi = (uint)f2bf(src[2]) | ((uint)f2bf(src[3]) << 16);
        uint2 pk; pk.x = lo; pk.y = hi;
        *(uint2*)(Vsw + ((size_t)(b * 4 + hh) * 1024 + (n0 >> 2) + sg) * 64 + d * 4) = pk;
    }
}

// ---------------------------------------------------------------------------
// attn: MFMA flash attention, no LDS, no barriers, no online max.
// Per wave: 32 queries. S^T = K*Q^T (32x32x16), p = exp2(s), PV via two
// 32x32x16 MFMAs whose k-slots are permuted to match the C-layout of S^T
// (so P never leaves registers). l = ones-row (d=16) of V's A-operand.
// grid 512 = 8 bh * 32 qblocks * 2 keysplit. block 256 (4 waves).
// ---------------------------------------------------------------------------
__global__ __launch_bounds__(256) void attn_kernel(
    const ushort* __restrict__ Qb, const ushort* __restrict__ Kb,
    const ushort* __restrict__ Vsw, float* __restrict__ AOp)
{
    const int t   = threadIdx.x;
    const int lid = t & 63;
    const int w   = t >> 6;
    const int c   = lid & 31;           // col / A-row
    const int h   = lid >> 5;           // k-slot group

    const int bi = blockIdx.x;
    const int kb = bi & 1;
    const int qb = (bi >> 1) & 31;
    const int bh = bi >> 6;
    const int nq = qb * 128 + w * 32;

    // Q B-frag: B[k=d=h*8+j][n=q=c]  (Q pre-scaled by 0.25*log2e)
    const bf16x8 qf = *(const bf16x8*)(Qb + ((size_t)bh * 4096 + nq + c) * 16 + h * 8);

    f32x16 oacc, zf;
    #pragma unroll
    for (int i = 0; i < 16; ++i) { oacc[i] = 0.f; zf[i] = 0.f; }

    const ushort* kp = Kb + ((size_t)bh * 4096 + kb * 2048 + c) * 16 + h * 8;
    const ushort* vb = Vsw + (size_t)bh * 65536 + ((size_t)kb * 512 + h) * 64 + c * 4;

    #pragma unroll 2
    for (int ch = 0; ch < 64; ++ch) {
        // S^T tile: A = K rows (keys), B = Q
        const bf16x8 kf = *(const bf16x8*)kp;
        f32x16 s = __builtin_amdgcn_mfma_f32_32x32x16_bf16(kf, qf, zf, 0, 0, 0);

        // p = exp2(s) packed to bf16; reg j of C-layout == B-frag slot j
        BF8 p1, p2;
        #pragma unroll
        for (int jj = 0; jj < 4; ++jj) {
            p1.u[jj] = pack_bf(__builtin_amdgcn_exp2f(s[2*jj]),     __builtin_amdgcn_exp2f(s[2*jj+1]));
            p2.u[jj] = pack_bf(__builtin_amdgcn_exp2f(s[8+2*jj]),   __builtin_amdgcn_exp2f(s[8+2*jj+1]));
        }

        // V A-frags, k-slots permuted to match C-layout rows:
        // slot (h,j) -> key (j&3) + 8*(j>>2) + 4h (+16 for frag 2)
        BF8 a1, a2;
        if (c < 16) {
            const uint2 g1 = *(const uint2*)(vb);
            const uint2 g2 = *(const uint2*)(vb + 128);
            const uint2 g3 = *(const uint2*)(vb + 256);
            const uint2 g4 = *(const uint2*)(vb + 384);
            a1.u[0] = g1.x; a1.u[1] = g1.y; a1.u[2] = g2.x; a1.u[3] = g2.y;
            a2.u[0] = g3.x; a2.u[1] = g3.y; a2.u[2] = g4.x; a2.u[3] = g4.y;
        } else {
            const uint f = (c == 16) ? 0x3F803F80u : 0u;   // ones row -> l
            a1.u[0] = a1.u[1] = a1.u[2] = a1.u[3] = f;
            a2.u[0] = a2.u[1] = a2.u[2] = a2.u[3] = f;
        }

        oacc = __builtin_amdgcn_mfma_f32_32x32x16_bf16(a1.v, p1.v, oacc, 0, 0, 0);
        oacc = __builtin_amdgcn_mfma_f32_32x32x16_bf16(a2.v, p2.v, oacc, 0, 0, 0);

        kp += 512; vb += 512;
    }

    // O^T C-layout: col=q=c, row = (reg&3)+8*(reg>>2)+4h; rows 0..15 = d, 16 = l
    float* ao = AOp + ((size_t)(kb * 8 + bh) * 17) * 4096 + nq + c;
    #pragma unroll
    for (int i = 0; i < 8; ++i) {
        int row = (i & 3) + 8 * (i >> 2) + 4 * h;
        ao[(size_t)row * 4096] = oacc[i];
    }
    if (h == 0) ao[(size_t)16 * 4096] = oacc[8];
}

// ---------------------------------------------------------------------------
// final: merge key-splits, /l, *dyn, out-proj [256x64] with s-reg weights,
// sigmoid(gamma*y + x). grid 128 = 2 b * 64 tiles(64 px). block 256.
// ---------------------------------------------------------------------------
__global__ __launch_bounds__(256) void final_kernel(
    const float* __restrict__ AOp, const float* __restrict__ dynb,
    const float* __restrict__ out_w, const float* __restrict__ x,
    const float* __restrict__ gamma, float* __restrict__ out)
{
    __shared__ float at[64 * 68];     // [px][r], stride 68
    __shared__ float lS[256];         // dyn/l per (h,px)

    const int t  = threadIdx.x;
    const int b  = blockIdx.x >> 6;
    const int n0 = (blockIdx.x & 63) * 64;

    {
        int hh = t >> 6, px = t & 63;
        const float* a0 = AOp + ((size_t)(b * 4 + hh) * 17 + 16) * 4096 + n0 + px;
        float l = a0[0] + a0[(size_t)8 * 17 * 4096];
        lS[hh * 64 + px] = dynb[(size_t)b * 4096 + n0 + px] / l;
    }
    __syncthreads();
    for (int i = 0; i < 16; ++i) {
        int idx = i * 256 + t;          // r = idx>>6, px = idx&63
        int r = idx >> 6, px = idx & 63;
        int hh = r >> 4;
        const float* a0 = AOp + ((size_t)(b * 4 + hh) * 17 + (r & 15)) * 4096 + n0 + px;
        float v = a0[0] + a0[(size_t)8 * 17 * 4096];
        at[px * 68 + r] = v * lS[hh * 64 + px];
    }
    __syncthreads();

    const int w    = t >> 6;
    const int lane = t & 63;            // = px
    const int ob   = __builtin_amdgcn_readfirstlane(w * 64);

    float acc[64];
    #pragma unroll
    for (int i = 0; i < 64; ++i) acc[i] = 0.f;

    const float4* av = (const float4*)(at + lane * 68);
    for (int chk = 0; chk < 8; ++chk) {
        const float* wc = out_w + (size_t)(ob + chk * 8) * 64;
        float* ac = acc + chk * 8;
        #pragma unroll 2
        for (int r4 = 0; r4 < 16; ++r4) {
            float4 xv = av[r4];
            #pragma unroll
            for (int o = 0; o < 8; ++o) {
                const float4 wv = *(const float4*)(wc + o * 64 + r4 * 4);
                ac[o] += wv.x * xv.x + wv.y * xv.y + wv.z * xv.z + wv.w * xv.w;
            }
        }
    }

    const float g = gamma[0];
    for (int i = 0; i < 64; ++i) {
        int cc = ob + i;
        size_t idx = ((size_t)b * 256 + cc) * 4096 + n0 + lane;
        float z = g * acc[i] + x[idx];
        out[idx] = 1.f / (1.f + __builtin_amdgcn_exp2f(-z * LOG2E));
    }
}

// ---------------------------------------------------------------------------
extern "C" void kernel_launch(void* const* d_in, const int* in_sizes, int n_in,
                              void* d_out, int out_size, void* d_ws, size_t ws_size,
                              hipStream_t stream)
{
    const float* x      = (const float*)d_in[0];
    const float* norm_w = (const float*)d_in[1];
    const float* norm_b = (const float*)d_in[2];
    const float* qkv_w  = (const float*)d_in[3];
    const float* out_w  = (const float*)d_in[4];
    const float* c1w    = (const float*)d_in[5];
    const float* c1b    = (const float*)d_in[6];
    const float* c2w    = (const float*)d_in[7];
    const float* c2b    = (const float*)d_in[8];
    const float* gamma  = (const float*)d_in[9];

    ushort* Qb  = (ushort*)d_ws;                 // 8*4096*16
    ushort* Kb  = Qb + 524288;
    ushort* Vsw = Kb + 524288;                   // 8*1024*16*4
    float*  AOp = (float*)(Vsw + 524288);        // 2*8*17*4096
    float*  dynb = AOp + 2 * 8 * 17 * 4096;      // 2*4096

    hipLaunchKernelGGL(prep_kernel, dim3(256), dim3(256), 0, stream,
                       x, norm_w, norm_b, qkv_w, c1w, c1b, c2w, c2b, Qb, Kb, Vsw, dynb);
    hipLaunchKernelGGL(attn_kernel, dim3(512), dim3(256), 0, stream,
                       Qb, Kb, Vsw, AOp);
    hipLaunchKernelGGL(final_kernel, dim3(128), dim3(256), 0, stream,
                       AOp, dynb, out_w, x, gamma, (float*)d_out);
}

// Round 3
// 139.312 us; speedup vs baseline: 3.7746x; 1.8617x over previous
//
#include <hip/hip_runtime.h>
#include <cstdint>
#include <cstddef>

#define LOG2E 1.44269504088896340736f

typedef float  f32x16 __attribute__((ext_vector_type(16)));
typedef __bf16 bf16x8 __attribute__((ext_vector_type(8)));

union BF8 { bf16x8 v; uint u[4]; ushort us[8]; };

// pack two floats to bf16 pair (round-half-up), a -> lo16, b -> hi16
__device__ __forceinline__ uint pack_bf(float a, float b) {
    uint ua = __float_as_uint(a) + 0x8000u;
    uint ub = __float_as_uint(b) + 0x8000u;
    return __builtin_amdgcn_perm(ub, ua, 0x07060302u);
}
__device__ __forceinline__ float bf_lo(uint u) { return __uint_as_float(u << 16); }
__device__ __forceinline__ float bf_hi(uint u) { return __uint_as_float(u & 0xFFFF0000u); }

// ---------------------------------------------------------------------------
// convert_w: fp32 -> bf16 weights. qkv_w rows o<64 (=Q) pre-scaled 0.25*log2e.
// concat layout: qkv_w[49152] | c1w[32768] | out_w[16384] = 98304 elems.
// grid 96 x 256, one float4 per thread.
// ---------------------------------------------------------------------------
__global__ __launch_bounds__(256) void convert_w_kernel(
    const float* __restrict__ qkv_w, const float* __restrict__ c1w,
    const float* __restrict__ out_w,
    ushort* __restrict__ qkvw_b, ushort* __restrict__ c1w_b, ushort* __restrict__ ow_b)
{
    const int g = (blockIdx.x * 256 + threadIdx.x) * 4;
    const float* src; ushort* dst; int off; float sc = 1.f;
    if (g < 49152)      { src = qkv_w; dst = qkvw_b; off = g;
                          if (g < 16384) sc = 0.25f * LOG2E; }
    else if (g < 81920) { src = c1w;   dst = c1w_b;  off = g - 49152; }
    else                { src = out_w; dst = ow_b;   off = g - 81920; }
    float4 v = *(const float4*)(src + off);
    uint2 pk;
    pk.x = pack_bf(v.x * sc, v.y * sc);
    pk.y = pack_bf(v.z * sc, v.w * sc);
    *(uint2*)(dst + off) = pk;
}

// ---------------------------------------------------------------------------
// ln_cast: per-pixel LayerNorm over 256 channels; emits xn_bf (normalized) and
// xr_bf (raw) as row-major bf16 [b*4096+n][256]. One block = 32 px.
// grid 256 x 256.
// ---------------------------------------------------------------------------
__global__ __launch_bounds__(256) void ln_cast_kernel(
    const float* __restrict__ x, const float* __restrict__ nw, const float* __restrict__ nb,
    ushort* __restrict__ xnb, ushort* __restrict__ xrb)
{
    __shared__ uint  xp[32 * 144];   // [px][c/2] bf16 pairs, stride 144 (2-way free)
    __shared__ float red1[256], red2[256];
    __shared__ float muS[32], rsS[32];

    const int t  = threadIdx.x;
    const int b  = blockIdx.x >> 7;
    const int n0 = (blockIdx.x & 127) * 32;
    const int j  = t & 31;          // px
    const int cg = t >> 5;          // channel group (32 c each)
    const size_t xb = (size_t)b * 256 * 4096 + n0 + j;

    float v[32];
    #pragma unroll
    for (int i = 0; i < 32; ++i) v[i] = x[xb + (size_t)(cg * 32 + i) * 4096];
    float s1 = 0.f, s2 = 0.f;
    #pragma unroll
    for (int i = 0; i < 32; ++i) { s1 += v[i]; s2 += v[i] * v[i]; }
    #pragma unroll
    for (int i = 0; i < 16; ++i)
        xp[j * 144 + cg * 16 + i] = pack_bf(v[2 * i], v[2 * i + 1]);
    red1[t] = s1; red2[t] = s2;
    __syncthreads();
    if (t < 32) {
        float a = 0.f, q = 0.f;
        #pragma unroll
        for (int g2 = 0; g2 < 8; ++g2) { a += red1[g2 * 32 + t]; q += red2[g2 * 32 + t]; }
        float mu  = a * (1.f / 256.f);
        float var = q * (1.f / 256.f) - mu * mu;
        muS[t] = mu; rsS[t] = rsqrtf(fmaxf(var, 0.f) + 1e-5f);
    }
    __syncthreads();

    for (int it = 0; it < 4; ++it) {
        int lin = it * 256 + t;
        int px = lin >> 5, q = lin & 31;          // q = uint4 slot (8 bf16)
        uint4 raw = *(uint4*)&xp[px * 144 + q * 4];
        size_t row = (size_t)blockIdx.x * 32 + px;       // = b*4096 + n0 + px
        *(uint4*)(xrb + row * 256 + q * 8) = raw;

        float mu = muS[px], rs = rsS[px];
        const float4 w0 = *(const float4*)(nw + q * 8);
        const float4 w1 = *(const float4*)(nw + q * 8 + 4);
        const float4 b0 = *(const float4*)(nb + q * 8);
        const float4 b1 = *(const float4*)(nb + q * 8 + 4);
        float e0 = (bf_lo(raw.x) - mu) * rs * w0.x + b0.x;
        float e1 = (bf_hi(raw.x) - mu) * rs * w0.y + b0.y;
        float e2 = (bf_lo(raw.y) - mu) * rs * w0.z + b0.z;
        float e3 = (bf_hi(raw.y) - mu) * rs * w0.w + b0.w;
        float e4 = (bf_lo(raw.z) - mu) * rs * w1.x + b1.x;
        float e5 = (bf_hi(raw.z) - mu) * rs * w1.y + b1.y;
        float e6 = (bf_lo(raw.w) - mu) * rs * w1.z + b1.z;
        float e7 = (bf_hi(raw.w) - mu) * rs * w1.w + b1.w;
        uint4 o;
        o.x = pack_bf(e0, e1); o.y = pack_bf(e2, e3);
        o.z = pack_bf(e4, e5); o.w = pack_bf(e6, e7);
        *(uint4*)(xnb + row * 256 + q * 8) = o;
    }
}

// ---------------------------------------------------------------------------
// qkvconv: MFMA GEMMs. Block = one 32-px group, 4 waves:
//   wave 0/1/2 = Q/K/V (64 outs = 2 tiles, A=weights, B=xn), wave 3 = conv
//   branch (128 outs = 4 tiles, B=xr) with relu*c2w reduction -> dynb.
// Epilogues via wave-private LDS transpose (stride 33, conflict-free).
// grid 256 x 256.
// ---------------------------------------------------------------------------
__global__ __launch_bounds__(256) void qkvconv_kernel(
    const ushort* __restrict__ xnb, const ushort* __restrict__ xrb,
    const ushort* __restrict__ qkvw_b, const ushort* __restrict__ c1w_b,
    const float* __restrict__ c1b, const float* __restrict__ c2w,
    const float* __restrict__ c2b,
    ushort* __restrict__ Qb, ushort* __restrict__ Kb, ushort* __restrict__ Vsw,
    float* __restrict__ dynb)
{
    __shared__ float trans[4][32 * 33];
    const int t    = threadIdx.x;
    const int w    = t >> 6;
    const int lane = t & 63;
    const int m    = lane & 31;       // A-row / C-col index
    const int h    = lane >> 5;       // k-slot half
    const int pg   = blockIdx.x;
    const int b    = pg >> 7;
    const int n0   = (pg & 127) * 32;
    float* tr = trans[w];

    if (w < 3) {
        const ushort* bp  = xnb + ((size_t)pg * 32 + m) * 256 + h * 8;
        const ushort* ap0 = qkvw_b + ((size_t)(w * 64 + m)) * 256 + h * 8;
        const ushort* ap1 = ap0 + 32 * 256;
        f32x16 acc0, acc1;
        #pragma unroll
        for (int i = 0; i < 16; ++i) { acc0[i] = 0.f; acc1[i] = 0.f; }
        #pragma unroll 4
        for (int ks = 0; ks < 16; ++ks) {
            bf16x8 bf = *(const bf16x8*)(bp  + ks * 16);
            bf16x8 a0 = *(const bf16x8*)(ap0 + ks * 16);
            bf16x8 a1 = *(const bf16x8*)(ap1 + ks * 16);
            acc0 = __builtin_amdgcn_mfma_f32_32x32x16_bf16(a0, bf, acc0, 0, 0, 0);
            acc1 = __builtin_amdgcn_mfma_f32_32x32x16_bf16(a1, bf, acc1, 0, 0, 0);
        }
        for (int ti = 0; ti < 2; ++ti) {
            const f32x16& A = ti ? acc1 : acc0;
            #pragma unroll
            for (int r = 0; r < 16; ++r)
                tr[((r & 3) + 8 * (r >> 2) + 4 * h) * 33 + m] = A[r];
            if (w < 2) {
                ushort* dst = (w == 0) ? Qb : Kb;
                #pragma unroll
                for (int it = 0; it < 2; ++it) {
                    int unit = it * 2 + h;            // 0..3
                    int hl = unit >> 1, half = unit & 1;
                    float v0 = tr[(hl * 16 + half * 8 + 0) * 33 + m];
                    float v1 = tr[(hl * 16 + half * 8 + 1) * 33 + m];
                    float v2 = tr[(hl * 16 + half * 8 + 2) * 33 + m];
                    float v3 = tr[(hl * 16 + half * 8 + 3) * 33 + m];
                    float v4 = tr[(hl * 16 + half * 8 + 4) * 33 + m];
                    float v5 = tr[(hl * 16 + half * 8 + 5) * 33 + m];
                    float v6 = tr[(hl * 16 + half * 8 + 6) * 33 + m];
                    float v7 = tr[(hl * 16 + half * 8 + 7) * 33 + m];
                    uint4 pk;
                    pk.x = pack_bf(v0, v1); pk.y = pack_bf(v2, v3);
                    pk.z = pack_bf(v4, v5); pk.w = pack_bf(v6, v7);
                    int head = ti * 2 + hl;
                    *(uint4*)(dst + ((size_t)(b * 4 + head) * 4096 + n0 + m) * 16 + half * 8) = pk;
                }
            } else {
                int d = lane & 15, u = lane >> 4;
                #pragma unroll
                for (int it = 0; it < 4; ++it) {
                    int unit = it * 4 + u;            // 0..15
                    int hl = unit >> 3, sg = unit & 7;
                    float v0 = tr[(hl * 16 + d) * 33 + sg * 4 + 0];
                    float v1 = tr[(hl * 16 + d) * 33 + sg * 4 + 1];
                    float v2 = tr[(hl * 16 + d) * 33 + sg * 4 + 2];
                    float v3 = tr[(hl * 16 + d) * 33 + sg * 4 + 3];
                    uint2 pk; pk.x = pack_bf(v0, v1); pk.y = pack_bf(v2, v3);
                    int head = ti * 2 + hl;
                    *(uint2*)(Vsw + (((size_t)(b * 4 + head) * 1024 + (pg & 127) * 8 + sg) * 16 + d) * 4) = pk;
                }
            }
        }
    } else {
        // conv branch: 4 tiles x 16 ksteps on raw x
        const ushort* bp = xrb + ((size_t)pg * 32 + m) * 256 + h * 8;
        f32x16 acc[4];
        #pragma unroll
        for (int ti = 0; ti < 4; ++ti)
            #pragma unroll
            for (int i = 0; i < 16; ++i) acc[ti][i] = 0.f;
        #pragma unroll 2
        for (int ks = 0; ks < 16; ++ks) {
            bf16x8 bf = *(const bf16x8*)(bp + ks * 16);
            #pragma unroll
            for (int ti = 0; ti < 4; ++ti) {
                bf16x8 a = *(const bf16x8*)(c1w_b + ((size_t)(ti * 32 + m)) * 256 + ks * 16 + h * 8);
                acc[ti] = __builtin_amdgcn_mfma_f32_32x32x16_bf16(a, bf, acc[ti], 0, 0, 0);
            }
        }
        float partial = 0.f;
        for (int ti = 0; ti < 4; ++ti) {
            #pragma unroll
            for (int r = 0; r < 16; ++r)
                tr[((r & 3) + 8 * (r >> 2) + 4 * h) * 33 + m] = acc[ti][r];
            #pragma unroll
            for (int i = 0; i < 16; ++i) {
                int og = ti * 32 + h * 16 + i;
                partial += fmaxf(tr[(h * 16 + i) * 33 + m] + c1b[og], 0.f) * c2w[og];
            }
        }
        float tot = partial + __shfl_xor(partial, 32);
        if (lane < 32) dynb[(size_t)b * 4096 + n0 + m] = c2b[0] + tot;
    }
}

// ---------------------------------------------------------------------------
// attn: MFMA flash attention (unchanged core). Epilogue writes AO2 rows
// [kb*8+bh][n][20]: d0..15 at 0..15, l at 16. grid 512 x 256.
// ---------------------------------------------------------------------------
__global__ __launch_bounds__(256) void attn_kernel(
    const ushort* __restrict__ Qb, const ushort* __restrict__ Kb,
    const ushort* __restrict__ Vsw, float* __restrict__ AO2)
{
    const int t   = threadIdx.x;
    const int lid = t & 63;
    const int w   = t >> 6;
    const int c   = lid & 31;
    const int h   = lid >> 5;

    const int bi = blockIdx.x;
    const int kb = bi & 1;
    const int qb = (bi >> 1) & 31;
    const int bh = bi >> 6;
    const int nq = qb * 128 + w * 32;

    const bf16x8 qf = *(const bf16x8*)(Qb + ((size_t)bh * 4096 + nq + c) * 16 + h * 8);

    f32x16 oacc, zf;
    #pragma unroll
    for (int i = 0; i < 16; ++i) { oacc[i] = 0.f; zf[i] = 0.f; }

    const ushort* kp = Kb + ((size_t)bh * 4096 + kb * 2048 + c) * 16 + h * 8;
    const ushort* vb = Vsw + (size_t)bh * 65536 + ((size_t)kb * 512 + h) * 64 + c * 4;

    #pragma unroll 2
    for (int ch = 0; ch < 64; ++ch) {
        const bf16x8 kf = *(const bf16x8*)kp;
        f32x16 s = __builtin_amdgcn_mfma_f32_32x32x16_bf16(kf, qf, zf, 0, 0, 0);

        BF8 p1, p2;
        #pragma unroll
        for (int jj = 0; jj < 4; ++jj) {
            p1.u[jj] = pack_bf(__builtin_amdgcn_exp2f(s[2*jj]),   __builtin_amdgcn_exp2f(s[2*jj+1]));
            p2.u[jj] = pack_bf(__builtin_amdgcn_exp2f(s[8+2*jj]), __builtin_amdgcn_exp2f(s[8+2*jj+1]));
        }

        BF8 a1, a2;
        if (c < 16) {
            const uint2 g1 = *(const uint2*)(vb);
            const uint2 g2 = *(const uint2*)(vb + 128);
            const uint2 g3 = *(const uint2*)(vb + 256);
            const uint2 g4 = *(const uint2*)(vb + 384);
            a1.u[0] = g1.x; a1.u[1] = g1.y; a1.u[2] = g2.x; a1.u[3] = g2.y;
            a2.u[0] = g3.x; a2.u[1] = g3.y; a2.u[2] = g4.x; a2.u[3] = g4.y;
        } else {
            const uint f = (c == 16) ? 0x3F803F80u : 0u;   // ones row -> l
            a1.u[0] = a1.u[1] = a1.u[2] = a1.u[3] = f;
            a2.u[0] = a2.u[1] = a2.u[2] = a2.u[3] = f;
        }

        oacc = __builtin_amdgcn_mfma_f32_32x32x16_bf16(a1.v, p1.v, oacc, 0, 0, 0);
        oacc = __builtin_amdgcn_mfma_f32_32x32x16_bf16(a2.v, p2.v, oacc, 0, 0, 0);

        kp += 512; vb += 512;
    }

    float* ao = AO2 + ((size_t)(kb * 8 + bh) * 4096 + nq + c) * 20;
    float4 s0; s0.x = oacc[0]; s0.y = oacc[1]; s0.z = oacc[2]; s0.w = oacc[3];
    float4 s1; s1.x = oacc[4]; s1.y = oacc[5]; s1.z = oacc[6]; s1.w = oacc[7];
    *(float4*)(ao + 4 * h)     = s0;     // d {0..3}+4h
    *(float4*)(ao + 8 + 4 * h) = s1;     // d {8..11}+4h
    if (h == 0) ao[16] = oacc[8];        // l
}

// ---------------------------------------------------------------------------
// final: MFMA out-proj. Per kstep ks (=head), lanes build B-frag from AO2
// (merge kb splits, /l, *dyn). A = out_w bf16. Epilogue via LDS transpose ->
// coalesced sigmoid(g*y + x) writes. grid 256 x 256.
// ---------------------------------------------------------------------------
__global__ __launch_bounds__(256) void final_kernel(
    const float* __restrict__ AO2, const float* __restrict__ dynb,
    const ushort* __restrict__ ow_b, const float* __restrict__ x,
    const float* __restrict__ gamma, float* __restrict__ out)
{
    __shared__ float trans[4][32 * 33];
    const int t    = threadIdx.x;
    const int w    = t >> 6;
    const int lane = t & 63;
    const int m    = lane & 31;      // px / A-row
    const int h    = lane >> 5;
    const int pg   = blockIdx.x;
    const int b    = pg >> 7;
    const int n0   = (pg & 127) * 32;
    float* tr = trans[w];

    const float dyn_px = dynb[(size_t)b * 4096 + n0 + m];
    const ushort* a0p = ow_b + ((size_t)(w * 64 + m)) * 64 + h * 8;
    const ushort* a1p = a0p + 32 * 64;

    f32x16 acc0, acc1;
    #pragma unroll
    for (int i = 0; i < 16; ++i) { acc0[i] = 0.f; acc1[i] = 0.f; }

    #pragma unroll
    for (int ks = 0; ks < 4; ++ks) {
        const float* r0 = AO2 + ((size_t)(b * 4 + ks) * 4096 + n0 + m) * 20;
        const float* r1 = r0 + (size_t)8 * 4096 * 20;
        float l   = r0[16] + r1[16];
        float fac = dyn_px / l;
        float4 u0 = *(const float4*)(r0 + h * 8);
        float4 u1 = *(const float4*)(r0 + h * 8 + 4);
        float4 t0 = *(const float4*)(r1 + h * 8);
        float4 t1 = *(const float4*)(r1 + h * 8 + 4);
        float e0 = (u0.x + t0.x) * fac, e1 = (u0.y + t0.y) * fac;
        float e2 = (u0.z + t0.z) * fac, e3 = (u0.w + t0.w) * fac;
        float e4 = (u1.x + t1.x) * fac, e5 = (u1.y + t1.y) * fac;
        float e6 = (u1.z + t1.z) * fac, e7 = (u1.w + t1.w) * fac;
        BF8 bfr;
        bfr.u[0] = pack_bf(e0, e1); bfr.u[1] = pack_bf(e2, e3);
        bfr.u[2] = pack_bf(e4, e5); bfr.u[3] = pack_bf(e6, e7);
        bf16x8 af0 = *(const bf16x8*)(a0p + ks * 16);
        bf16x8 af1 = *(const bf16x8*)(a1p + ks * 16);
        acc0 = __builtin_amdgcn_mfma_f32_32x32x16_bf16(af0, bfr.v, acc0, 0, 0, 0);
        acc1 = __builtin_amdgcn_mfma_f32_32x32x16_bf16(af1, bfr.v, acc1, 0, 0, 0);
    }

    const float g = gamma[0];
    for (int ti = 0; ti < 2; ++ti) {
        const f32x16& A = ti ? acc1 : acc0;
        #pragma unroll
        for (int r = 0; r < 16; ++r)
            tr[((r & 3) + 8 * (r >> 2) + 4 * h) * 33 + m] = A[r];
        int ob = w * 64 + ti * 32;
        #pragma unroll 4
        for (int it = 0; it < 16; ++it) {
            int o = it * 2 + h;
            float vv = tr[o * 33 + m];
            size_t idx = ((size_t)b * 256 + ob + o) * 4096 + n0 + m;
            float z = g * vv + x[idx];
            out[idx] = 1.f / (1.f + __builtin_amdgcn_exp2f(-z * LOG2E));
        }
    }
}

// ---------------------------------------------------------------------------
extern "C" void kernel_launch(void* const* d_in, const int* in_sizes, int n_in,
                              void* d_out, int out_size, void* d_ws, size_t ws_size,
                              hipStream_t stream)
{
    const float* x      = (const float*)d_in[0];
    const float* norm_w = (const float*)d_in[1];
    const float* norm_b = (const float*)d_in[2];
    const float* qkv_w  = (const float*)d_in[3];
    const float* out_w  = (const float*)d_in[4];
    const float* c1w    = (const float*)d_in[5];
    const float* c1b    = (const float*)d_in[6];
    const float* c2w    = (const float*)d_in[7];
    const float* c2b    = (const float*)d_in[8];
    const float* gamma  = (const float*)d_in[9];

    char* ws = (char*)d_ws;
    ushort* Qb     = (ushort*)ws;                       // 524288 ush (1 MB)
    ushort* Kb     = Qb + 524288;
    ushort* Vsw    = Kb + 524288;                       // 524288 ush
    ushort* qkvw_b = Vsw + 524288;                      // 49152
    ushort* c1w_b  = qkvw_b + 49152;                    // 32768
    ushort* ow_b   = c1w_b + 32768;                     // 16384
    float*  dynb   = (float*)(ws + 3342336);            // 8192 floats
    // region X (byte 3375104): xn/xr live ln->qkvconv; AO2 aliases xn after
    ushort* xnb    = (ushort*)(ws + 3375104);           // 2097152 ush (4 MB)
    ushort* xrb    = xnb + 2097152;                     // 4 MB
    float*  AO2    = (float*)(ws + 3375104);            // 2*8*4096*20 fp32 (5.24 MB)

    hipLaunchKernelGGL(convert_w_kernel, dim3(96), dim3(256), 0, stream,
                       qkv_w, c1w, out_w, qkvw_b, c1w_b, ow_b);
    hipLaunchKernelGGL(ln_cast_kernel, dim3(256), dim3(256), 0, stream,
                       x, norm_w, norm_b, xnb, xrb);
    hipLaunchKernelGGL(qkvconv_kernel, dim3(256), dim3(256), 0, stream,
                       xnb, xrb, qkvw_b, c1w_b, c1b, c2w, c2b, Qb, Kb, Vsw, dynb);
    hipLaunchKernelGGL(attn_kernel, dim3(512), dim3(256), 0, stream,
                       Qb, Kb, Vsw, AO2);
    hipLaunchKernelGGL(final_kernel, dim3(256), dim3(256), 0, stream,
                       AO2, dynb, ow_b, x, gamma, (float*)d_out);
}